// Round 5
// baseline (384.010 us; speedup 1.0000x reference)
//
#include <hip/hip_runtime.h>
#include <hip/hip_bf16.h>
#include <cstdint>
#include <cstddef>

// MultiHeadAttention: fp32 in/out. B=4, L=2048, D=1024, H=16, dk=64.
// bf16 MFMA internally, fp32 accumulation.

typedef unsigned short u16;
typedef __bf16 bf8v __attribute__((ext_vector_type(8)));   // MFMA A/B frag (4 VGPRs)
typedef __bf16 bf4v __attribute__((ext_vector_type(4)));
typedef float f32x4 __attribute__((ext_vector_type(4)));   // MFMA C/D frag

#define D_MODEL 1024
#define NHEAD   16
#define DK      64
#define BATCH   4
#define SEQ     2048
#define ROWS    (BATCH * SEQ)   // 8192

__device__ __forceinline__ u16 f2b(float f) {  // RTNE float->bf16
  union { float f; unsigned int i; } x; x.f = f;
  unsigned int r = x.i + 0x7fffu + ((x.i >> 16) & 1u);
  return (u16)(r >> 16);
}
__device__ __forceinline__ ushort4 pack4(float a, float b, float c, float d) {
  union { bf4v v; ushort4 u; } x;
  x.v[0] = (__bf16)a; x.v[1] = (__bf16)b; x.v[2] = (__bf16)c; x.v[3] = (__bf16)d;
  return x.u;
}
__device__ __forceinline__ bf8v cvt8(float4 a, float4 b) {  // v_cvt_pk_bf16_f32 x4
  bf8v r;
  r[0] = (__bf16)a.x; r[1] = (__bf16)a.y; r[2] = (__bf16)a.z; r[3] = (__bf16)a.w;
  r[4] = (__bf16)b.x; r[5] = (__bf16)b.y; r[6] = (__bf16)b.z; r[7] = (__bf16)b.w;
  return r;
}
__device__ __forceinline__ void async16(const void* g, void* l) {
  __builtin_amdgcn_global_load_lds((const __attribute__((address_space(1))) void*)g,
                                   (__attribute__((address_space(3))) void*)l, 16, 0, 0);
}
#define MFMA16(a, b, c) __builtin_amdgcn_mfma_f32_16x16x32_bf16(a, b, c, 0, 0, 0)

// -------- weight transpose + downcast: dst[n][k] = bf16(src[k][n]), 4 mats ------
__global__ void wtrans_cvt_kernel(const float* __restrict__ w0, const float* __restrict__ w1,
                                  const float* __restrict__ w2, const float* __restrict__ w3,
                                  u16* __restrict__ dst4) {
  __shared__ float t[32][33];
  const float* src = (blockIdx.z == 0) ? w0 : (blockIdx.z == 1) ? w1
                   : (blockIdx.z == 2) ? w2 : w3;
  u16* dst = dst4 + (size_t)blockIdx.z * D_MODEL * D_MODEL;
  const int c0 = blockIdx.x * 32, r0 = blockIdx.y * 32;
  for (int i = threadIdx.y; i < 32; i += 8)
    t[i][threadIdx.x] = src[(size_t)(r0 + i) * D_MODEL + c0 + threadIdx.x];
  __syncthreads();
  for (int i = threadIdx.y; i < 32; i += 8)
    dst[(size_t)(c0 + i) * D_MODEL + r0 + threadIdx.x] = f2b(t[threadIdx.x][i]);
}

// ---------------- fused QKV projection GEMM (batched z = 0,1,2) -----------------
// A = fp32 activations (cvt fused into A-staging: reg-load a full iter ahead ->
// cvt_pk -> ds_write_b128). B = bf16 W^T via global_load_lds.
// DOUBLE-BUFFERED K-loop, ONE barrier per K-step: stage tile t+1 into buf p^1 at
// the top of iter t, compute tile t from buf p (attn_kernel's proven schedule —
// round-4 counters showed the old stage->barrier->compute loop exposed full
// memory latency every step: MfmaUtil 14.6%, 1780 cy/K-step vs ~310 of MFMA).
// z=0: Qw [bh][l][dk] *QSCALE; z=1: Kw same; z=2: Vt [bh][dk][pi(l)].
// Epilogues: z<2 operand-swapped MFMA -> ushort4 stores; z=2 packs the
// 4-consecutive pi(l) run. XCD chunk map: xcd = lid&7 owns 8 contiguous
// m-panels x all n -> A-panel fetched once/XCD, B (2MB) L2-resident.
#define BM 128
#define BN 128
#define BK 32

__global__ __launch_bounds__(256, 2) void gemm_qkv(
    const float* __restrict__ Aq, const float* __restrict__ Ak,
    const float* __restrict__ Av, const u16* __restrict__ wt,
    const float* __restrict__ bq, const float* __restrict__ bk,
    const float* __restrict__ bv, u16* __restrict__ Qw, u16* __restrict__ Kw,
    u16* __restrict__ Vt, float qscale) {
  __shared__ __align__(16) u16 As[2][BM * BK];  // 16 KB
  __shared__ __align__(16) u16 Bs[2][BN * BK];  // 16 KB
  const int z = blockIdx.y;
  const float* A = (z == 0) ? Aq : (z == 1) ? Ak : Av;
  const u16* Bt = wt + (size_t)z * D_MODEL * D_MODEL;
  const float* bias = (z == 0) ? bq : (z == 1) ? bk : bv;
  u16* out = (z == 0) ? Qw : (z == 1) ? Kw : Vt;
  const float oscale = (z == 0) ? qscale : 1.0f;

  const int lid = blockIdx.x;               // 512 blocks: 8 xcd x 8 m x 8 n
  const int xcd = lid & 7, jj = lid >> 3;
  const int m0 = ((xcd << 3) + (jj >> 3)) * BM;
  const int n0 = (jj & 7) * BN;

  const int tid = threadIdx.x;
  const int lane = tid & 63, wave = tid >> 6;
  const int wm = wave >> 1, wn = wave & 1;
  const int quad = lane >> 4, l16 = lane & 15;
  const int K = 1024;

  f32x4 acc[4][4];
#pragma unroll
  for (int i = 0; i < 4; i++)
#pragma unroll
    for (int j = 0; j < 4; j++) acc[i][j] = (f32x4){0.f, 0.f, 0.f, 0.f};

  const int srow = tid >> 2;
  const int sch = ((tid & 3) ^ ((tid >> 3) & 3)) * 8;
  const int fsw = (quad ^ ((l16 >> 1) & 3)) * 8;
  const float* Ag0 = A + (size_t)(m0 + srow) * K + sch;
  const float* Ag1 = Ag0 + (size_t)64 * K;
  const u16* Bg = Bt + (size_t)(n0 + srow) * K + sch;

  // prologue: stage tile 0 into buf 0; preload A regs for tile 1
  float4 a0 = *(const float4*)(Ag0);
  float4 a1 = *(const float4*)(Ag0 + 4);
  float4 a2 = *(const float4*)(Ag1);
  float4 a3 = *(const float4*)(Ag1 + 4);
  async16(Bg, &Bs[0][tid * 8]);
  async16(Bg + (size_t)64 * K, &Bs[0][2048 + tid * 8]);
  *(bf8v*)&As[0][tid * 8]        = cvt8(a0, a1);
  *(bf8v*)&As[0][2048 + tid * 8] = cvt8(a2, a3);
  a0 = *(const float4*)(Ag0 + BK);
  a1 = *(const float4*)(Ag0 + BK + 4);
  a2 = *(const float4*)(Ag1 + BK);
  a3 = *(const float4*)(Ag1 + BK + 4);
  __syncthreads();

  int p = 0;
  for (int k0 = 0; k0 < K; k0 += BK) {
    const int kn = k0 + BK;
    if (kn < K) {  // stage tile t+1 into buf p^1 (drained by end-of-iter barrier)
      async16(Bg + kn, &Bs[p ^ 1][tid * 8]);
      async16(Bg + (size_t)64 * K + kn, &Bs[p ^ 1][2048 + tid * 8]);
      *(bf8v*)&As[p ^ 1][tid * 8]        = cvt8(a0, a1);
      *(bf8v*)&As[p ^ 1][2048 + tid * 8] = cvt8(a2, a3);
      if (kn + BK < K) {  // preload A regs for tile t+2 (full iter to land)
        a0 = *(const float4*)(Ag0 + kn + BK);
        a1 = *(const float4*)(Ag0 + kn + BK + 4);
        a2 = *(const float4*)(Ag1 + kn + BK);
        a3 = *(const float4*)(Ag1 + kn + BK + 4);
      }
    }

    bf8v af[4], bfr[4];
#pragma unroll
    for (int i = 0; i < 4; i++)
      af[i] = *(const bf8v*)&As[p][(wm * 64 + i * 16 + l16) * BK + fsw];
#pragma unroll
    for (int j = 0; j < 4; j++)
      bfr[j] = *(const bf8v*)&Bs[p][(wn * 64 + j * 16 + l16) * BK + fsw];
    if (z < 2) {
#pragma unroll
      for (int i = 0; i < 4; i++)
#pragma unroll
        for (int j = 0; j < 4; j++)
          acc[i][j] = MFMA16(bfr[j], af[i], acc[i][j]);  // swapped: col=m, row=n
    } else {
#pragma unroll
      for (int i = 0; i < 4; i++)
#pragma unroll
        for (int j = 0; j < 4; j++)
          acc[i][j] = MFMA16(af[i], bfr[j], acc[i][j]);  // col=n, row=m
    }
    __syncthreads();
    p ^= 1;
  }

  if (z < 2) {
    // swapped C: m = m0+wm*64+i*16+l16, n = n0+wn*64+j*16+quad*4+r
#pragma unroll
    for (int i = 0; i < 4; i++) {
      const int m = m0 + wm * 64 + i * 16 + l16;
      const int b = m >> 11, l = m & 2047;
#pragma unroll
      for (int j = 0; j < 4; j++) {
        const int n = n0 + wn * 64 + j * 16 + quad * 4;
        const float4 bv4 = *(const float4*)&bias[n];
        const int h = n >> 6, d = n & 63;
        *(ushort4*)&out[(((size_t)(b * NHEAD + h) * SEQ + l) << 6) + d] =
            pack4((acc[i][j][0] + bv4.x) * oscale, (acc[i][j][1] + bv4.y) * oscale,
                  (acc[i][j][2] + bv4.z) * oscale, (acc[i][j][3] + bv4.w) * oscale);
      }
    }
  } else {
    // unswapped C: n = n0+wn*64+j*16+l16 (lane = d), rows l = ...+quad*4+r
#pragma unroll
    for (int j = 0; j < 4; j++) {
      const int n = n0 + wn * 64 + j * 16 + l16;
      const float bvs = bias[n];
      const int h = n >> 6, d = n & 63;
#pragma unroll
      for (int i = 0; i < 4; i++) {
        const int row = m0 + wm * 64 + i * 16 + quad * 4;
        const int b = row >> 11, l = row & 2047;
        // pi: k=16h'+4q'+r' -> 8q'+4h'+r'; l 4-aligned => pl_base + r
        const int pl = (l & ~31) | ((l & 12) << 1) | ((l & 16) >> 2);
        *(ushort4*)&out[(((size_t)(b * NHEAD + h) * DK + d) << 11) + pl] =
            pack4(acc[i][j][0] + bvs, acc[i][j][1] + bvs,
                  acc[i][j][2] + bvs, acc[i][j][3] + bvs);
      }
    }
  }
}

// ---------------- output projection GEMM: out fp32 = ctx @ Wo^T + bo ------------
// A = bf16 ctx; double-buffered async16 staging (one barrier per K-step),
// swapped MFMA, float4 stores (full 64B lines).
__global__ __launch_bounds__(256, 2) void gemm_out(const u16* __restrict__ A,
                                                   const u16* __restrict__ Bt,
                                                   const float* __restrict__ bias,
                                                   float* __restrict__ out) {
  __shared__ __align__(16) u16 As[2][BM * BK];
  __shared__ __align__(16) u16 Bs[2][BN * BK];
  const int lid = blockIdx.x;
  const int xcd = lid & 7, jj = lid >> 3;
  const int m0 = ((xcd << 3) + (jj >> 3)) * BM;
  const int n0 = (jj & 7) * BN;
  const int tid = threadIdx.x;
  const int lane = tid & 63, wave = tid >> 6;
  const int wm = wave >> 1, wn = wave & 1;
  const int quad = lane >> 4, l16 = lane & 15;
  const int K = 1024;

  f32x4 acc[4][4];
#pragma unroll
  for (int i = 0; i < 4; i++)
#pragma unroll
    for (int j = 0; j < 4; j++) acc[i][j] = (f32x4){0.f, 0.f, 0.f, 0.f};

  const int srow = tid >> 2;
  const int sch = ((tid & 3) ^ ((tid >> 3) & 3)) * 8;
  const int fsw = (quad ^ ((l16 >> 1) & 3)) * 8;
  const u16* Ag = A + (size_t)(m0 + srow) * K + sch;
  const u16* Bg = Bt + (size_t)(n0 + srow) * K + sch;

  // prologue: stage tile 0 into buf 0
  async16(Ag, &As[0][tid * 8]);
  async16(Ag + (size_t)64 * K, &As[0][2048 + tid * 8]);
  async16(Bg, &Bs[0][tid * 8]);
  async16(Bg + (size_t)64 * K, &Bs[0][2048 + tid * 8]);
  __syncthreads();

  int p = 0;
  for (int k0 = 0; k0 < K; k0 += BK) {
    const int kn = k0 + BK;
    if (kn < K) {  // prefetch tile t+1 into buf p^1
      async16(Ag + kn, &As[p ^ 1][tid * 8]);
      async16(Ag + (size_t)64 * K + kn, &As[p ^ 1][2048 + tid * 8]);
      async16(Bg + kn, &Bs[p ^ 1][tid * 8]);
      async16(Bg + (size_t)64 * K + kn, &Bs[p ^ 1][2048 + tid * 8]);
    }

    bf8v af[4], bfr[4];
#pragma unroll
    for (int i = 0; i < 4; i++)
      af[i] = *(const bf8v*)&As[p][(wm * 64 + i * 16 + l16) * BK + fsw];
#pragma unroll
    for (int j = 0; j < 4; j++)
      bfr[j] = *(const bf8v*)&Bs[p][(wn * 64 + j * 16 + l16) * BK + fsw];
#pragma unroll
    for (int i = 0; i < 4; i++)
#pragma unroll
      for (int j = 0; j < 4; j++)
        acc[i][j] = MFMA16(bfr[j], af[i], acc[i][j]);  // swapped: col=m, row=n
    __syncthreads();
    p ^= 1;
  }

#pragma unroll
  for (int i = 0; i < 4; i++) {
    const int m = m0 + wm * 64 + i * 16 + l16;
#pragma unroll
    for (int j = 0; j < 4; j++) {
      const int n = n0 + wn * 64 + j * 16 + quad * 4;
      const float4 bv4 = *(const float4*)&bias[n];
      float4 vv;
      vv.x = acc[i][j][0] + bv4.x; vv.y = acc[i][j][1] + bv4.y;
      vv.z = acc[i][j][2] + bv4.z; vv.w = acc[i][j][3] + bv4.w;
      *(float4*)&out[(size_t)m * D_MODEL + n] = vv;
    }
  }
}

// ---------------- flash attention (S^T form): block = 128 q rows x one bh -------
// (unchanged -- 97.3 us, 0 bank conflicts, FETCH 25 MB)
__global__ __launch_bounds__(256, 4) void attn_kernel(const u16* __restrict__ Q,
                                                      const u16* __restrict__ K,
                                                      const u16* __restrict__ Vt,
                                                      u16* __restrict__ ctx) {
  const int bh = blockIdx.x;
  const int qb = blockIdx.y * 128;
  const int tid = threadIdx.x;
  const int lane = tid & 63, wave = tid >> 6;
  const int quad = lane >> 4, l16 = lane & 15;
  const u16* Qh = Q + (size_t)bh * SEQ * DK;
  const u16* Kh = K + (size_t)bh * SEQ * DK;
  const u16* Vh = Vt + (size_t)bh * DK * SEQ;

  __shared__ __align__(16) u16 Ks[2][2][64 * 32];  // [buf][d-half][key][32 d swz] 16 KB
  __shared__ __align__(16) u16 Vs[2][64 * 64];     // [buf][d][64 keys, chunk^d&7] 16 KB

  const int srow = tid >> 2;
  const int sch  = ((tid & 3) ^ ((tid >> 3) & 3)) * 8;
  const int ldst = tid * 8;
  const int fsw  = (quad ^ ((l16 >> 1) & 3)) * 8;
  const int vd   = tid >> 3;
  const int vcol = ((tid & 7) ^ ((tid >> 3) & 7)) * 8;

  bf8v qf[2][2];
#pragma unroll
  for (int qg = 0; qg < 2; qg++)
#pragma unroll
    for (int h = 0; h < 2; h++)
      qf[qg][h] = *(const bf8v*)&Qh[(size_t)(qb + wave * 32 + qg * 16 + l16) * DK + h * 32 + quad * 8];

  bf8v ones;
#pragma unroll
  for (int j = 0; j < 8; j++) ones[j] = (__bf16)1.0f;

  f32x4 o[2][4];
  f32x4 la[2];
  float m_q[2];
#pragma unroll
  for (int qg = 0; qg < 2; qg++) {
    m_q[qg] = -1e30f; la[qg] = (f32x4){0.f, 0.f, 0.f, 0.f};
#pragma unroll
    for (int d = 0; d < 4; d++) o[qg][d] = (f32x4){0.f, 0.f, 0.f, 0.f};
  }

  async16(Kh + (size_t)srow * DK + sch,      &Ks[0][0][ldst]);
  async16(Kh + (size_t)srow * DK + 32 + sch, &Ks[0][1][ldst]);
  async16(Vh + (size_t)vd * SEQ + vcol,        &Vs[0][ldst]);
  async16(Vh + (size_t)(vd + 32) * SEQ + vcol, &Vs[0][2048 + ldst]);
  __syncthreads();

  int p = 0;
  for (int kt = 0; kt < SEQ; kt += 64) {
    const int nt = kt + 64;
    if (nt < SEQ) {
      async16(Kh + (size_t)(nt + srow) * DK + sch,      &Ks[p ^ 1][0][ldst]);
      async16(Kh + (size_t)(nt + srow) * DK + 32 + sch, &Ks[p ^ 1][1][ldst]);
      async16(Vh + (size_t)vd * SEQ + nt + vcol,        &Vs[p ^ 1][ldst]);
      async16(Vh + (size_t)(vd + 32) * SEQ + nt + vcol, &Vs[p ^ 1][2048 + ldst]);
    }

    bf8v kf[4][2];
#pragma unroll
    for (int nb = 0; nb < 4; nb++)
#pragma unroll
      for (int h = 0; h < 2; h++)
        kf[nb][h] = *(const bf8v*)&Ks[p][h][(nb * 16 + l16) * 32 + fsw];

    bf8v pf[2][2];
#pragma unroll
    for (int qg = 0; qg < 2; qg++) {
      f32x4 s[4];
      __builtin_amdgcn_s_setprio(1);
#pragma unroll
      for (int nb = 0; nb < 4; nb++) {
        f32x4 t = (f32x4){0.f, 0.f, 0.f, 0.f};
        t = MFMA16(kf[nb][0], qf[qg][0], t);
        t = MFMA16(kf[nb][1], qf[qg][1], t);
        s[nb] = t;
      }
      __builtin_amdgcn_s_setprio(0);
      float t0 = fmaxf(fmaxf(s[0][0], s[0][1]), fmaxf(s[0][2], s[0][3]));
      float t1 = fmaxf(fmaxf(s[1][0], s[1][1]), fmaxf(s[1][2], s[1][3]));
      float t2 = fmaxf(fmaxf(s[2][0], s[2][1]), fmaxf(s[2][2], s[2][3]));
      float t3 = fmaxf(fmaxf(s[3][0], s[3][1]), fmaxf(s[3][2], s[3][3]));
      float mx = fmaxf(fmaxf(t0, t1), fmaxf(t2, t3));
      mx = fmaxf(mx, __shfl_xor(mx, 16));
      mx = fmaxf(mx, __shfl_xor(mx, 32));
      const float mprev = m_q[qg];
      float Mn = mprev;
      const int resc = !__all(mx - mprev <= 8.0f);
      if (resc) {
        Mn = fmaxf(mprev, mx);
        const float al = __builtin_amdgcn_exp2f(mprev - Mn);
        m_q[qg] = Mn;
        la[qg] *= al;
#pragma unroll
        for (int d = 0; d < 4; d++) o[qg][d] *= al;
      }
#pragma unroll
      for (int nb = 0; nb < 4; nb++)
#pragma unroll
        for (int r = 0; r < 4; r++)
          s[nb][r] = __builtin_amdgcn_exp2f(s[nb][r] - Mn);
#pragma unroll
      for (int kc = 0; kc < 2; kc++) {
        bf8v pw;
#pragma unroll
        for (int j = 0; j < 4; j++) {
          pw[j]     = (__bf16)s[2 * kc][j];
          pw[j + 4] = (__bf16)s[2 * kc + 1][j];
        }
        pf[qg][kc] = pw;
      }
      la[qg] = MFMA16(ones, pf[qg][0], la[qg]);
      la[qg] = MFMA16(ones, pf[qg][1], la[qg]);
    }

    bf8v vf[4][2];
#pragma unroll
    for (int dc = 0; dc < 4; dc++) {
      const int rb = (dc * 16 + l16) * 64;
#pragma unroll
      for (int kc = 0; kc < 2; kc++)
        vf[dc][kc] = *(const bf8v*)&Vs[p][rb + (((kc * 4 + quad) ^ (l16 & 7)) * 8)];
    }
    __builtin_amdgcn_s_setprio(1);
#pragma unroll
    for (int qg = 0; qg < 2; qg++)
#pragma unroll
      for (int dc = 0; dc < 4; dc++) {
        o[qg][dc] = MFMA16(vf[dc][0], pf[qg][0], o[qg][dc]);
        o[qg][dc] = MFMA16(vf[dc][1], pf[qg][1], o[qg][dc]);
      }
    __builtin_amdgcn_s_setprio(0);

    __syncthreads();
    p ^= 1;
  }

  const int b = bh >> 4, hh = bh & 15;
#pragma unroll
  for (int qg = 0; qg < 2; qg++) {
    const float inv = __builtin_amdgcn_rcpf(la[qg][0]);
    const int q = qb + wave * 32 + qg * 16 + l16;
#pragma unroll
    for (int dc = 0; dc < 4; dc++) {
      const int col = hh * 64 + dc * 16 + quad * 4;
      *(ushort4*)&ctx[(size_t)(b * SEQ + q) * D_MODEL + col] =
          pack4(o[qg][dc][0] * inv, o[qg][dc][1] * inv,
                o[qg][dc][2] * inv, o[qg][dc][3] * inv);
    }
  }
}

// -------------------------------- launch ---------------------------------------
extern "C" void kernel_launch(void* const* d_in, const int* in_sizes, int n_in,
                              void* d_out, int out_size, void* d_ws, size_t ws_size,
                              hipStream_t stream) {
  const float* q  = (const float*)d_in[0];
  const float* k  = (const float*)d_in[1];
  const float* v  = (const float*)d_in[2];
  const float* Wq = (const float*)d_in[3];
  const float* bq = (const float*)d_in[4];
  const float* Wk = (const float*)d_in[5];
  const float* bk = (const float*)d_in[6];
  const float* Wv = (const float*)d_in[7];
  const float* bv = (const float*)d_in[8];
  const float* Wo = (const float*)d_in[9];
  const float* bo = (const float*)d_in[10];

  u16* ws  = (u16*)d_ws;
  u16* wt  = ws;                                     // 4 x 1M bf16 (W^T x4) = 8 MB
  u16* Qw  = wt + (size_t)4 * D_MODEL * D_MODEL;
  u16* Kw  = Qw + (size_t)ROWS * D_MODEL;
  u16* Vt  = Kw + (size_t)ROWS * D_MODEL;
  u16* ctx = Vt + (size_t)ROWS * D_MODEL;            // total ~75.6 MB

  const float QSCALE = 0.18033688011112042f;  // 0.125 * log2(e) -> exp2-domain softmax

  wtrans_cvt_kernel<<<dim3(32, 32, 4), dim3(32, 8), 0, stream>>>(Wq, Wk, Wv, Wo, wt);

  gemm_qkv<<<dim3(512, 3), 256, 0, stream>>>(q, k, v, wt, bq, bk, bv, Qw, Kw, Vt, QSCALE);

  attn_kernel<<<dim3(BATCH * NHEAD, SEQ / 128), 256, 0, stream>>>(Qw, Kw, Vt, ctx);

  gemm_out<<<512, 256, 0, stream>>>(ctx, wt + (size_t)3 * D_MODEL * D_MODEL, bo,
                                    (float*)d_out);
}

// Round 6
// 352.916 us; speedup vs baseline: 1.0881x; 1.0881x over previous
//
#include <hip/hip_runtime.h>
#include <hip/hip_bf16.h>
#include <cstdint>
#include <cstddef>

// MultiHeadAttention: fp32 in/out. B=4, L=2048, D=1024, H=16, dk=64.
// bf16 MFMA internally, fp32 accumulation.

typedef unsigned short u16;
typedef __bf16 bf8v __attribute__((ext_vector_type(8)));   // MFMA A/B frag (4 VGPRs)
typedef __bf16 bf4v __attribute__((ext_vector_type(4)));
typedef float f32x4 __attribute__((ext_vector_type(4)));   // MFMA C/D frag

#define D_MODEL 1024
#define NHEAD   16
#define DK      64
#define BATCH   4
#define SEQ     2048
#define ROWS    (BATCH * SEQ)   // 8192

__device__ __forceinline__ u16 f2b(float f) {  // RTNE float->bf16
  union { float f; unsigned int i; } x; x.f = f;
  unsigned int r = x.i + 0x7fffu + ((x.i >> 16) & 1u);
  return (u16)(r >> 16);
}
__device__ __forceinline__ ushort4 pack4(float a, float b, float c, float d) {
  union { bf4v v; ushort4 u; } x;
  x.v[0] = (__bf16)a; x.v[1] = (__bf16)b; x.v[2] = (__bf16)c; x.v[3] = (__bf16)d;
  return x.u;
}
__device__ __forceinline__ bf8v cvt8(float4 a, float4 b) {  // v_cvt_pk_bf16_f32 x4
  bf8v r;
  r[0] = (__bf16)a.x; r[1] = (__bf16)a.y; r[2] = (__bf16)a.z; r[3] = (__bf16)a.w;
  r[4] = (__bf16)b.x; r[5] = (__bf16)b.y; r[6] = (__bf16)b.z; r[7] = (__bf16)b.w;
  return r;
}
__device__ __forceinline__ void async16(const void* g, void* l) {
  __builtin_amdgcn_global_load_lds((const __attribute__((address_space(1))) void*)g,
                                   (__attribute__((address_space(3))) void*)l, 16, 0, 0);
}
#define MFMA16(a, b, c) __builtin_amdgcn_mfma_f32_16x16x32_bf16(a, b, c, 0, 0, 0)

// -------- weight transpose + downcast: dst[n][k] = bf16(src[k][n]), 4 mats ------
__global__ void wtrans_cvt_kernel(const float* __restrict__ w0, const float* __restrict__ w1,
                                  const float* __restrict__ w2, const float* __restrict__ w3,
                                  u16* __restrict__ dst4) {
  __shared__ float t[32][33];
  const float* src = (blockIdx.z == 0) ? w0 : (blockIdx.z == 1) ? w1
                   : (blockIdx.z == 2) ? w2 : w3;
  u16* dst = dst4 + (size_t)blockIdx.z * D_MODEL * D_MODEL;
  const int c0 = blockIdx.x * 32, r0 = blockIdx.y * 32;
  for (int i = threadIdx.y; i < 32; i += 8)
    t[i][threadIdx.x] = src[(size_t)(r0 + i) * D_MODEL + c0 + threadIdx.x];
  __syncthreads();
  for (int i = threadIdx.y; i < 32; i += 8)
    dst[(size_t)(c0 + i) * D_MODEL + r0 + threadIdx.x] = f2b(t[threadIdx.x][i]);
}

// ---------------- fused QKV projection GEMM (batched z = 0,1,2) -----------------
// BK=64: per-K-step compute (32 MFMA + 16 ds_read_b128, ~600-700 cy) now covers
// the HBM latency of the staging issued at the top of the same step — round-5
// counters showed BK=32's ~350 cy window left ~600 cy of A-load latency exposed
// at every barrier (970 cy/step measured vs ~350 ideal). 16 steps instead of 32.
// A = fp32 activations, cvt fused into staging (reg-load one iter ahead ->
// cvt_pk -> ds_write_b128, swizzled). B = bf16 W^T via async16 (source
// pre-swizzled). LDS swizzle: 8 chunks of 8 u16 per 128B row, chunk ^= (row>>1)&7.
// z=0: Qw [bh][l][dk] *QSCALE; z=1: Kw same; z=2: Vt [bh][dk][pi(l)].
// XCD chunk map: xcd = lid&7 owns 8 contiguous m-panels x all n.
#define BM 128
#define BN 128
#define BK 64
#define NT (1024 / BK)

__global__ __launch_bounds__(256, 2) void gemm_qkv(
    const float* __restrict__ Aq, const float* __restrict__ Ak,
    const float* __restrict__ Av, const u16* __restrict__ wt,
    const float* __restrict__ bq, const float* __restrict__ bk,
    const float* __restrict__ bv, u16* __restrict__ Qw, u16* __restrict__ Kw,
    u16* __restrict__ Vt, float qscale) {
  __shared__ __align__(16) u16 As[2][BM * BK];  // 32 KB
  __shared__ __align__(16) u16 Bs[2][BN * BK];  // 32 KB
  const int z = blockIdx.y;
  const float* A = (z == 0) ? Aq : (z == 1) ? Ak : Av;
  const u16* Bt = wt + (size_t)z * D_MODEL * D_MODEL;
  const float* bias = (z == 0) ? bq : (z == 1) ? bk : bv;
  u16* out = (z == 0) ? Qw : (z == 1) ? Kw : Vt;
  const float oscale = (z == 0) ? qscale : 1.0f;

  const int lid = blockIdx.x;               // 512 blocks: 8 xcd x 8 m x 8 n
  const int xcd = lid & 7, jj = lid >> 3;
  const int m0 = ((xcd << 3) + (jj >> 3)) * BM;
  const int n0 = (jj & 7) * BN;

  const int tid = threadIdx.x;
  const int lane = tid & 63, wave = tid >> 6;
  const int wm = wave >> 1, wn = wave & 1;
  const int quad = lane >> 4, l16 = lane & 15;
  const int K = 1024;

  f32x4 acc[4][4];
#pragma unroll
  for (int i = 0; i < 4; i++)
#pragma unroll
    for (int j = 0; j < 4; j++) acc[i][j] = (f32x4){0.f, 0.f, 0.f, 0.f};

  // staging map: thread covers row s8 = tid>>3 (+32 per instr m), swizzled chunk
  const int s8 = tid >> 3;
  const int lc = ((tid & 7) ^ ((tid >> 4) & 7)) * 8;   // key = (row>>1)&7
  const int fk = (l16 >> 1) & 7;                        // frag-read swizzle key
  const float* Agt = A + (size_t)(m0 + s8) * K + lc;
  const u16* Bgt = Bt + (size_t)(n0 + s8) * K + lc;

  // prologue: stage tile 0 into buf 0; preload A regs for tile 1
  float4 ar[8];
#pragma unroll
  for (int m = 0; m < 4; m++) {
    ar[2 * m]     = *(const float4*)(Agt + (size_t)m * 32 * K);
    ar[2 * m + 1] = *(const float4*)(Agt + (size_t)m * 32 * K + 4);
  }
#pragma unroll
  for (int m = 0; m < 4; m++)
    async16(Bgt + (size_t)m * 32 * K, &Bs[0][m * 2048 + tid * 8]);
#pragma unroll
  for (int m = 0; m < 4; m++)
    *(bf8v*)&As[0][m * 2048 + tid * 8] = cvt8(ar[2 * m], ar[2 * m + 1]);
#pragma unroll
  for (int m = 0; m < 4; m++) {
    ar[2 * m]     = *(const float4*)(Agt + (size_t)m * 32 * K + BK);
    ar[2 * m + 1] = *(const float4*)(Agt + (size_t)m * 32 * K + BK + 4);
  }
  __syncthreads();

  int p = 0;
  for (int t = 0; t < NT; t++) {
    const int kn = (t + 1) * BK;
    if (kn < K) {  // stage tile t+1 into buf p^1 (covered by this iter's compute)
#pragma unroll
      for (int m = 0; m < 4; m++)
        async16(Bgt + (size_t)m * 32 * K + kn, &Bs[p ^ 1][m * 2048 + tid * 8]);
#pragma unroll
      for (int m = 0; m < 4; m++)
        *(bf8v*)&As[p ^ 1][m * 2048 + tid * 8] = cvt8(ar[2 * m], ar[2 * m + 1]);
      if (kn + BK < K) {  // preload A regs for tile t+2
#pragma unroll
        for (int m = 0; m < 4; m++) {
          ar[2 * m]     = *(const float4*)(Agt + (size_t)m * 32 * K + kn + BK);
          ar[2 * m + 1] = *(const float4*)(Agt + (size_t)m * 32 * K + kn + BK + 4);
        }
      }
    }

    bf8v af[4][2], bfr[4][2];
#pragma unroll
    for (int i = 0; i < 4; i++)
#pragma unroll
      for (int h = 0; h < 2; h++)
        af[i][h] = *(const bf8v*)&As[p][(wm * 64 + i * 16 + l16) * BK +
                                        (((h * 4 + quad) ^ fk) * 8)];
#pragma unroll
    for (int j = 0; j < 4; j++)
#pragma unroll
      for (int h = 0; h < 2; h++)
        bfr[j][h] = *(const bf8v*)&Bs[p][(wn * 64 + j * 16 + l16) * BK +
                                         (((h * 4 + quad) ^ fk) * 8)];
    __builtin_amdgcn_s_setprio(1);
    if (z < 2) {
#pragma unroll
      for (int i = 0; i < 4; i++)
#pragma unroll
        for (int j = 0; j < 4; j++) {
          acc[i][j] = MFMA16(bfr[j][0], af[i][0], acc[i][j]);  // swapped: col=m
          acc[i][j] = MFMA16(bfr[j][1], af[i][1], acc[i][j]);
        }
    } else {
#pragma unroll
      for (int i = 0; i < 4; i++)
#pragma unroll
        for (int j = 0; j < 4; j++) {
          acc[i][j] = MFMA16(af[i][0], bfr[j][0], acc[i][j]);  // col=n, row=m
          acc[i][j] = MFMA16(af[i][1], bfr[j][1], acc[i][j]);
        }
    }
    __builtin_amdgcn_s_setprio(0);
    __syncthreads();
    p ^= 1;
  }

  if (z < 2) {
    // swapped C: m = m0+wm*64+i*16+l16, n = n0+wn*64+j*16+quad*4+r
#pragma unroll
    for (int i = 0; i < 4; i++) {
      const int m = m0 + wm * 64 + i * 16 + l16;
      const int b = m >> 11, l = m & 2047;
#pragma unroll
      for (int j = 0; j < 4; j++) {
        const int n = n0 + wn * 64 + j * 16 + quad * 4;
        const float4 bv4 = *(const float4*)&bias[n];
        const int h = n >> 6, d = n & 63;
        *(ushort4*)&out[(((size_t)(b * NHEAD + h) * SEQ + l) << 6) + d] =
            pack4((acc[i][j][0] + bv4.x) * oscale, (acc[i][j][1] + bv4.y) * oscale,
                  (acc[i][j][2] + bv4.z) * oscale, (acc[i][j][3] + bv4.w) * oscale);
      }
    }
  } else {
    // unswapped C: n = n0+wn*64+j*16+l16 (lane = d), rows l = ...+quad*4+r
#pragma unroll
    for (int j = 0; j < 4; j++) {
      const int n = n0 + wn * 64 + j * 16 + l16;
      const float bvs = bias[n];
      const int h = n >> 6, d = n & 63;
#pragma unroll
      for (int i = 0; i < 4; i++) {
        const int row = m0 + wm * 64 + i * 16 + quad * 4;
        const int b = row >> 11, l = row & 2047;
        // pi: k=16h'+4q'+r' -> 8q'+4h'+r'; l 4-aligned => pl_base + r
        const int pl = (l & ~31) | ((l & 12) << 1) | ((l & 16) >> 2);
        *(ushort4*)&out[(((size_t)(b * NHEAD + h) * DK + d) << 11) + pl] =
            pack4(acc[i][j][0] + bvs, acc[i][j][1] + bvs,
                  acc[i][j][2] + bvs, acc[i][j][3] + bvs);
      }
    }
  }
}

// ---------------- output projection GEMM: out fp32 = ctx @ Wo^T + bo ------------
// A = bf16 ctx; BK=64 double-buffered async16 staging (8 async16/step), swapped
// MFMA, float4 stores (full 64B lines).
__global__ __launch_bounds__(256, 2) void gemm_out(const u16* __restrict__ A,
                                                   const u16* __restrict__ Bt,
                                                   const float* __restrict__ bias,
                                                   float* __restrict__ out) {
  __shared__ __align__(16) u16 As[2][BM * BK];
  __shared__ __align__(16) u16 Bs[2][BN * BK];
  const int lid = blockIdx.x;
  const int xcd = lid & 7, jj = lid >> 3;
  const int m0 = ((xcd << 3) + (jj >> 3)) * BM;
  const int n0 = (jj & 7) * BN;
  const int tid = threadIdx.x;
  const int lane = tid & 63, wave = tid >> 6;
  const int wm = wave >> 1, wn = wave & 1;
  const int quad = lane >> 4, l16 = lane & 15;
  const int K = 1024;

  f32x4 acc[4][4];
#pragma unroll
  for (int i = 0; i < 4; i++)
#pragma unroll
    for (int j = 0; j < 4; j++) acc[i][j] = (f32x4){0.f, 0.f, 0.f, 0.f};

  const int s8 = tid >> 3;
  const int lc = ((tid & 7) ^ ((tid >> 4) & 7)) * 8;
  const int fk = (l16 >> 1) & 7;
  const u16* Agt = A + (size_t)(m0 + s8) * K + lc;
  const u16* Bgt = Bt + (size_t)(n0 + s8) * K + lc;

  // prologue: stage tile 0 into buf 0
#pragma unroll
  for (int m = 0; m < 4; m++) {
    async16(Agt + (size_t)m * 32 * K, &As[0][m * 2048 + tid * 8]);
    async16(Bgt + (size_t)m * 32 * K, &Bs[0][m * 2048 + tid * 8]);
  }
  __syncthreads();

  int p = 0;
  for (int t = 0; t < NT; t++) {
    const int kn = (t + 1) * BK;
    if (kn < K) {  // prefetch tile t+1 into buf p^1
#pragma unroll
      for (int m = 0; m < 4; m++) {
        async16(Agt + (size_t)m * 32 * K + kn, &As[p ^ 1][m * 2048 + tid * 8]);
        async16(Bgt + (size_t)m * 32 * K + kn, &Bs[p ^ 1][m * 2048 + tid * 8]);
      }
    }

    bf8v af[4][2], bfr[4][2];
#pragma unroll
    for (int i = 0; i < 4; i++)
#pragma unroll
      for (int h = 0; h < 2; h++)
        af[i][h] = *(const bf8v*)&As[p][(wm * 64 + i * 16 + l16) * BK +
                                        (((h * 4 + quad) ^ fk) * 8)];
#pragma unroll
    for (int j = 0; j < 4; j++)
#pragma unroll
      for (int h = 0; h < 2; h++)
        bfr[j][h] = *(const bf8v*)&Bs[p][(wn * 64 + j * 16 + l16) * BK +
                                         (((h * 4 + quad) ^ fk) * 8)];
    __builtin_amdgcn_s_setprio(1);
#pragma unroll
    for (int i = 0; i < 4; i++)
#pragma unroll
      for (int j = 0; j < 4; j++) {
        acc[i][j] = MFMA16(bfr[j][0], af[i][0], acc[i][j]);  // swapped: col=m
        acc[i][j] = MFMA16(bfr[j][1], af[i][1], acc[i][j]);
      }
    __builtin_amdgcn_s_setprio(0);
    __syncthreads();
    p ^= 1;
  }

#pragma unroll
  for (int i = 0; i < 4; i++) {
    const int m = m0 + wm * 64 + i * 16 + l16;
#pragma unroll
    for (int j = 0; j < 4; j++) {
      const int n = n0 + wn * 64 + j * 16 + quad * 4;
      const float4 bv4 = *(const float4*)&bias[n];
      float4 vv;
      vv.x = acc[i][j][0] + bv4.x; vv.y = acc[i][j][1] + bv4.y;
      vv.z = acc[i][j][2] + bv4.z; vv.w = acc[i][j][3] + bv4.w;
      *(float4*)&out[(size_t)m * D_MODEL + n] = vv;
    }
  }
}

// ---------------- flash attention (S^T form): block = 128 q rows x one bh -------
// (unchanged -- 97.3 us, 0 bank conflicts, FETCH 25 MB)
__global__ __launch_bounds__(256, 4) void attn_kernel(const u16* __restrict__ Q,
                                                      const u16* __restrict__ K,
                                                      const u16* __restrict__ Vt,
                                                      u16* __restrict__ ctx) {
  const int bh = blockIdx.x;
  const int qb = blockIdx.y * 128;
  const int tid = threadIdx.x;
  const int lane = tid & 63, wave = tid >> 6;
  const int quad = lane >> 4, l16 = lane & 15;
  const u16* Qh = Q + (size_t)bh * SEQ * DK;
  const u16* Kh = K + (size_t)bh * SEQ * DK;
  const u16* Vh = Vt + (size_t)bh * DK * SEQ;

  __shared__ __align__(16) u16 Ks[2][2][64 * 32];  // [buf][d-half][key][32 d swz] 16 KB
  __shared__ __align__(16) u16 Vs[2][64 * 64];     // [buf][d][64 keys, chunk^d&7] 16 KB

  const int srow = tid >> 2;
  const int sch  = ((tid & 3) ^ ((tid >> 3) & 3)) * 8;
  const int ldst = tid * 8;
  const int fsw  = (quad ^ ((l16 >> 1) & 3)) * 8;
  const int vd   = tid >> 3;
  const int vcol = ((tid & 7) ^ ((tid >> 3) & 7)) * 8;

  bf8v qf[2][2];
#pragma unroll
  for (int qg = 0; qg < 2; qg++)
#pragma unroll
    for (int h = 0; h < 2; h++)
      qf[qg][h] = *(const bf8v*)&Qh[(size_t)(qb + wave * 32 + qg * 16 + l16) * DK + h * 32 + quad * 8];

  bf8v ones;
#pragma unroll
  for (int j = 0; j < 8; j++) ones[j] = (__bf16)1.0f;

  f32x4 o[2][4];
  f32x4 la[2];
  float m_q[2];
#pragma unroll
  for (int qg = 0; qg < 2; qg++) {
    m_q[qg] = -1e30f; la[qg] = (f32x4){0.f, 0.f, 0.f, 0.f};
#pragma unroll
    for (int d = 0; d < 4; d++) o[qg][d] = (f32x4){0.f, 0.f, 0.f, 0.f};
  }

  async16(Kh + (size_t)srow * DK + sch,      &Ks[0][0][ldst]);
  async16(Kh + (size_t)srow * DK + 32 + sch, &Ks[0][1][ldst]);
  async16(Vh + (size_t)vd * SEQ + vcol,        &Vs[0][ldst]);
  async16(Vh + (size_t)(vd + 32) * SEQ + vcol, &Vs[0][2048 + ldst]);
  __syncthreads();

  int p = 0;
  for (int kt = 0; kt < SEQ; kt += 64) {
    const int nt = kt + 64;
    if (nt < SEQ) {
      async16(Kh + (size_t)(nt + srow) * DK + sch,      &Ks[p ^ 1][0][ldst]);
      async16(Kh + (size_t)(nt + srow) * DK + 32 + sch, &Ks[p ^ 1][1][ldst]);
      async16(Vh + (size_t)vd * SEQ + nt + vcol,        &Vs[p ^ 1][ldst]);
      async16(Vh + (size_t)(vd + 32) * SEQ + nt + vcol, &Vs[p ^ 1][2048 + ldst]);
    }

    bf8v kf[4][2];
#pragma unroll
    for (int nb = 0; nb < 4; nb++)
#pragma unroll
      for (int h = 0; h < 2; h++)
        kf[nb][h] = *(const bf8v*)&Ks[p][h][(nb * 16 + l16) * 32 + fsw];

    bf8v pf[2][2];
#pragma unroll
    for (int qg = 0; qg < 2; qg++) {
      f32x4 s[4];
      __builtin_amdgcn_s_setprio(1);
#pragma unroll
      for (int nb = 0; nb < 4; nb++) {
        f32x4 t = (f32x4){0.f, 0.f, 0.f, 0.f};
        t = MFMA16(kf[nb][0], qf[qg][0], t);
        t = MFMA16(kf[nb][1], qf[qg][1], t);
        s[nb] = t;
      }
      __builtin_amdgcn_s_setprio(0);
      float t0 = fmaxf(fmaxf(s[0][0], s[0][1]), fmaxf(s[0][2], s[0][3]));
      float t1 = fmaxf(fmaxf(s[1][0], s[1][1]), fmaxf(s[1][2], s[1][3]));
      float t2 = fmaxf(fmaxf(s[2][0], s[2][1]), fmaxf(s[2][2], s[2][3]));
      float t3 = fmaxf(fmaxf(s[3][0], s[3][1]), fmaxf(s[3][2], s[3][3]));
      float mx = fmaxf(fmaxf(t0, t1), fmaxf(t2, t3));
      mx = fmaxf(mx, __shfl_xor(mx, 16));
      mx = fmaxf(mx, __shfl_xor(mx, 32));
      const float mprev = m_q[qg];
      float Mn = mprev;
      const int resc = !__all(mx - mprev <= 8.0f);
      if (resc) {
        Mn = fmaxf(mprev, mx);
        const float al = __builtin_amdgcn_exp2f(mprev - Mn);
        m_q[qg] = Mn;
        la[qg] *= al;
#pragma unroll
        for (int d = 0; d < 4; d++) o[qg][d] *= al;
      }
#pragma unroll
      for (int nb = 0; nb < 4; nb++)
#pragma unroll
        for (int r = 0; r < 4; r++)
          s[nb][r] = __builtin_amdgcn_exp2f(s[nb][r] - Mn);
#pragma unroll
      for (int kc = 0; kc < 2; kc++) {
        bf8v pw;
#pragma unroll
        for (int j = 0; j < 4; j++) {
          pw[j]     = (__bf16)s[2 * kc][j];
          pw[j + 4] = (__bf16)s[2 * kc + 1][j];
        }
        pf[qg][kc] = pw;
      }
      la[qg] = MFMA16(ones, pf[qg][0], la[qg]);
      la[qg] = MFMA16(ones, pf[qg][1], la[qg]);
    }

    bf8v vf[4][2];
#pragma unroll
    for (int dc = 0; dc < 4; dc++) {
      const int rb = (dc * 16 + l16) * 64;
#pragma unroll
      for (int kc = 0; kc < 2; kc++)
        vf[dc][kc] = *(const bf8v*)&Vs[p][rb + (((kc * 4 + quad) ^ (l16 & 7)) * 8)];
    }
    __builtin_amdgcn_s_setprio(1);
#pragma unroll
    for (int qg = 0; qg < 2; qg++)
#pragma unroll
      for (int dc = 0; dc < 4; dc++) {
        o[qg][dc] = MFMA16(vf[dc][0], pf[qg][0], o[qg][dc]);
        o[qg][dc] = MFMA16(vf[dc][1], pf[qg][1], o[qg][dc]);
      }
    __builtin_amdgcn_s_setprio(0);

    __syncthreads();
    p ^= 1;
  }

  const int b = bh >> 4, hh = bh & 15;
#pragma unroll
  for (int qg = 0; qg < 2; qg++) {
    const float inv = __builtin_amdgcn_rcpf(la[qg][0]);
    const int q = qb + wave * 32 + qg * 16 + l16;
#pragma unroll
    for (int dc = 0; dc < 4; dc++) {
      const int col = hh * 64 + dc * 16 + quad * 4;
      *(ushort4*)&ctx[(size_t)(b * SEQ + q) * D_MODEL + col] =
          pack4(o[qg][dc][0] * inv, o[qg][dc][1] * inv,
                o[qg][dc][2] * inv, o[qg][dc][3] * inv);
    }
  }
}

// -------------------------------- launch ---------------------------------------
extern "C" void kernel_launch(void* const* d_in, const int* in_sizes, int n_in,
                              void* d_out, int out_size, void* d_ws, size_t ws_size,
                              hipStream_t stream) {
  const float* q  = (const float*)d_in[0];
  const float* k  = (const float*)d_in[1];
  const float* v  = (const float*)d_in[2];
  const float* Wq = (const float*)d_in[3];
  const float* bq = (const float*)d_in[4];
  const float* Wk = (const float*)d_in[5];
  const float* bk = (const float*)d_in[6];
  const float* Wv = (const float*)d_in[7];
  const float* bv = (const float*)d_in[8];
  const float* Wo = (const float*)d_in[9];
  const float* bo = (const float*)d_in[10];

  u16* ws  = (u16*)d_ws;
  u16* wt  = ws;                                     // 4 x 1M bf16 (W^T x4) = 8 MB
  u16* Qw  = wt + (size_t)4 * D_MODEL * D_MODEL;
  u16* Kw  = Qw + (size_t)ROWS * D_MODEL;
  u16* Vt  = Kw + (size_t)ROWS * D_MODEL;
  u16* ctx = Vt + (size_t)ROWS * D_MODEL;            // total ~75.6 MB

  const float QSCALE = 0.18033688011112042f;  // 0.125 * log2(e) -> exp2-domain softmax

  wtrans_cvt_kernel<<<dim3(32, 32, 4), dim3(32, 8), 0, stream>>>(Wq, Wk, Wv, Wo, wt);

  gemm_qkv<<<dim3(512, 3), 256, 0, stream>>>(q, k, v, wt, bq, bk, bv, Qw, Kw, Vt, QSCALE);

  attn_kernel<<<dim3(BATCH * NHEAD, SEQ / 128), 256, 0, stream>>>(Qw, Kw, Vt, ctx);

  gemm_out<<<512, 256, 0, stream>>>(ctx, wt + (size_t)3 * D_MODEL * D_MODEL, bo,
                                    (float*)d_out);
}